// Round 1
// baseline (602.098 us; speedup 1.0000x reference)
//
#include <hip/hip_runtime.h>
#include <hip/hip_bf16.h>

#define N 8192
#define D 512
#define K_TOP 12
#define THETA 10.0f
#define EPS 1e-8f
#define NSLICE 8
#define SLICE_J 1024
#define LDA 72  // padded row stride in bf16 elems (144 B; 2-way LDS conflict only)

typedef float f32x4 __attribute__((ext_vector_type(4)));
typedef short bf16x8 __attribute__((ext_vector_type(8)));

// ---------------- Kernel 0: row norms + bf16 normalized copy ----------------
__global__ __launch_bounds__(256) void norm_kernel(const float* __restrict__ h,
                                                   __hip_bfloat16* __restrict__ hn) {
    int row = blockIdx.x * 4 + (threadIdx.x >> 6);
    int lane = threadIdx.x & 63;
    const float* hr = h + (size_t)row * D;
    float v[8];
    float ss = 0.f;
#pragma unroll
    for (int e = 0; e < 8; e++) { v[e] = hr[lane + 64 * e]; ss += v[e] * v[e]; }
#pragma unroll
    for (int off = 32; off > 0; off >>= 1) ss += __shfl_xor(ss, off, 64);
    float inv = 1.0f / fmaxf(sqrtf(ss), EPS);
    __hip_bfloat16* hw = hn + (size_t)row * D;
#pragma unroll
    for (int e = 0; e < 8; e++) hw[lane + 64 * e] = __float2bfloat16(v[e] * inv);
}

// ---------------- Kernel 1: MFMA sim tiles + per-slice top-12 ----------------
// grid (64, 8): block = (i-tile of 128 rows) x (j-slice of 1024 cols, 8 tiles of 128)
__global__ __launch_bounds__(256) void simtop_kernel(const unsigned short* __restrict__ hn,
                                                     float2* __restrict__ cand) {
    __shared__ union {
        struct {
            unsigned short A[128][LDA];
            unsigned short B[128][LDA];
        } st;
        float S64[64][129];  // one 64-row half of the 128x128 S tile
    } u;
    __shared__ float topv[128][K_TOP];
    __shared__ int topi[128][K_TOP];

    const int bi = blockIdx.x;      // i-tile
    const int sl = blockIdx.y;      // j-slice
    const int i0 = bi * 128;
    const int t = threadIdx.x;
    const int wave = t >> 6, lane = t & 63;
    const int wr = (wave >> 1) * 64, wc = (wave & 1) * 64;
    const int lm = lane & 15, lg = lane >> 4;

    // per-thread running-min state for the two rows this thread scans
    float minv0 = -1e30f, minv1 = -1e30f;
    int mins0 = 0, mins1 = 0;
    if (t < 128) {
#pragma unroll
        for (int q = 0; q < K_TOP; q++) { topv[t][q] = -1e30f; topi[t][q] = 0; }
    }

    for (int jt = 0; jt < 8; jt++) {
        const int j0 = sl * SLICE_J + jt * 128;
        f32x4 acc[4][4];
#pragma unroll
        for (int x = 0; x < 4; x++)
#pragma unroll
            for (int y = 0; y < 4; y++) acc[x][y] = (f32x4){0.f, 0.f, 0.f, 0.f};

        for (int ks = 0; ks < 8; ks++) {
            const int k0 = ks * 64;
            __syncthreads();  // staging region free (prev reads / prev-jt scans done)
#pragma unroll
            for (int e = 0; e < 4; e++) {
                int lin = t + 256 * e;          // 0..1023 -> 16B chunks of a 128x64 tile
                int r = lin >> 3;
                int c = (lin & 7) * 8;
                *(uint4*)(&u.st.A[r][c]) =
                    *(const uint4*)(hn + (size_t)(i0 + r) * D + k0 + c);
                *(uint4*)(&u.st.B[r][c]) =
                    *(const uint4*)(hn + (size_t)(j0 + r) * D + k0 + c);
            }
            __syncthreads();
#pragma unroll
            for (int kk = 0; kk < 64; kk += 32) {
                bf16x8 af[4], bfr[4];
#pragma unroll
                for (int x = 0; x < 4; x++) {
                    af[x] = *(const bf16x8*)(&u.st.A[wr + x * 16 + lm][kk + lg * 8]);
                    bfr[x] = *(const bf16x8*)(&u.st.B[wc + x * 16 + lm][kk + lg * 8]);
                }
#pragma unroll
                for (int x = 0; x < 4; x++)
#pragma unroll
                    for (int y = 0; y < 4; y++)
                        acc[x][y] = __builtin_amdgcn_mfma_f32_16x16x32_bf16(
                            af[x], bfr[y], acc[x][y], 0, 0, 0);
            }
        }
        __syncthreads();  // all MFMA LDS reads done; reuse union as S

        // ---- rows 0..63 (waves 0,1) ----
        if (wave < 2) {
#pragma unroll
            for (int x = 0; x < 4; x++)
#pragma unroll
                for (int y = 0; y < 4; y++)
#pragma unroll
                    for (int r = 0; r < 4; r++)
                        u.S64[x * 16 + lg * 4 + r][wc + y * 16 + lm] = acc[x][y][r];
        }
        __syncthreads();
        if (t < 64) {
            if (i0 == j0) u.S64[t][t] = 1.0f;  // exact self-similarity
            for (int c = 0; c < 128; c++) {
                float v = u.S64[t][c];
                if (v > minv0) {
                    topv[t][mins0] = v;
                    topi[t][mins0] = j0 + c;
                    float mv = topv[t][0];
                    int ms = 0;
#pragma unroll
                    for (int q = 1; q < K_TOP; q++) {
                        float xq = topv[t][q];
                        if (xq < mv) { mv = xq; ms = q; }
                    }
                    minv0 = mv; mins0 = ms;
                }
            }
        }
        __syncthreads();  // scans of lower half done

        // ---- rows 64..127 (waves 2,3) ----
        if (wave >= 2) {
#pragma unroll
            for (int x = 0; x < 4; x++)
#pragma unroll
                for (int y = 0; y < 4; y++)
#pragma unroll
                    for (int r = 0; r < 4; r++)
                        u.S64[x * 16 + lg * 4 + r][wc + y * 16 + lm] = acc[x][y][r];
        }
        __syncthreads();
        if (t < 64) {
            int row = 64 + t;
            if (i0 == j0) u.S64[t][64 + t] = 1.0f;
            for (int c = 0; c < 128; c++) {
                float v = u.S64[t][c];
                if (v > minv1) {
                    topv[row][mins1] = v;
                    topi[row][mins1] = j0 + c;
                    float mv = topv[row][0];
                    int ms = 0;
#pragma unroll
                    for (int q = 1; q < K_TOP; q++) {
                        float xq = topv[row][q];
                        if (xq < mv) { mv = xq; ms = q; }
                    }
                    minv1 = mv; mins1 = ms;
                }
            }
        }
        // next jt's first __syncthreads() protects S64/stage reuse
    }
    __syncthreads();
    if (t < 128) {
        size_t base = ((size_t)(i0 + t) * NSLICE + sl) * K_TOP;
#pragma unroll
        for (int q = 0; q < K_TOP; q++)
            cand[base + q] = make_float2(topv[t][q], __int_as_float(topi[t][q]));
    }
}

// ---------------- Kernel 2: merge candidates, softmax, gather ----------------
__global__ __launch_bounds__(256) void gather_kernel(const float* __restrict__ h,
                                                     const float2* __restrict__ cand,
                                                     float* __restrict__ out) {
    int row = blockIdx.x * 4 + (threadIdx.x >> 6);
    int lane = threadIdx.x & 63;
    const float2* cr = cand + (size_t)row * (NSLICE * K_TOP);  // 96 candidates
    float2 c0 = cr[lane];
    float2 c1 = (lane < 32) ? cr[64 + lane] : make_float2(-1e30f, 0.f);

    float selv[K_TOP];
    int selj[K_TOP];
#pragma unroll
    for (int q = 0; q < K_TOP; q++) {
        float v; int meta; float idxf;
        if (c0.x >= c1.x) { v = c0.x; meta = lane * 2; idxf = c0.y; }
        else              { v = c1.x; meta = lane * 2 + 1; idxf = c1.y; }
#pragma unroll
        for (int off = 32; off > 0; off >>= 1) {
            float ov = __shfl_down(v, off, 64);
            int om = __shfl_down(meta, off, 64);
            float oi = __shfl_down(idxf, off, 64);
            if (ov > v || (ov == v && om < meta)) { v = ov; meta = om; idxf = oi; }
        }
        v = __shfl(v, 0, 64);
        meta = __shfl(meta, 0, 64);
        idxf = __shfl(idxf, 0, 64);
        selv[q] = v;
        selj[q] = __float_as_int(idxf);
        if (lane == (meta >> 1)) {
            if (meta & 1) c1.x = -1e30f;
            else c0.x = -1e30f;
        }
    }
    // softmax over 12 (selv[0] is the max — first extracted)
    float mx = selv[0];
    float beta[K_TOP];
    float sum = 0.f;
#pragma unroll
    for (int q = 0; q < K_TOP; q++) { beta[q] = __expf(THETA * (selv[q] - mx)); sum += beta[q]; }
    float rs = 1.0f / sum;

    float acc[8];
#pragma unroll
    for (int e = 0; e < 8; e++) acc[e] = 0.f;
#pragma unroll
    for (int q = 0; q < K_TOP; q++) {
        const float* hr = h + (size_t)selj[q] * D;
        float b = beta[q] * rs;
#pragma unroll
        for (int e = 0; e < 8; e++) acc[e] += b * hr[lane + 64 * e];
    }
    float* orow = out + (size_t)row * D;
#pragma unroll
    for (int e = 0; e < 8; e++) orow[lane + 64 * e] = acc[e];
}

extern "C" void kernel_launch(void* const* d_in, const int* in_sizes, int n_in,
                              void* d_out, int out_size, void* d_ws, size_t ws_size,
                              hipStream_t stream) {
    const float* h = (const float*)d_in[0];
    float* out = (float*)d_out;
    __hip_bfloat16* hn = (__hip_bfloat16*)d_ws;
    float2* cand = (float2*)((char*)d_ws + (size_t)N * D * sizeof(__hip_bfloat16));

    norm_kernel<<<N / 4, 256, 0, stream>>>(h, hn);
    dim3 grid(64, NSLICE);
    simtop_kernel<<<grid, 256, 0, stream>>>((const unsigned short*)hn, cand);
    gather_kernel<<<N / 4, 256, 0, stream>>>(h, cand, out);
}

// Round 3
// 302.723 us; speedup vs baseline: 1.9889x; 1.9889x over previous
//
#include <hip/hip_runtime.h>
#include <hip/hip_bf16.h>

#define N 8192
#define D 512
#define K_TOP 12
#define THETA 10.0f
#define EPS 1e-8f
#define NSLICE 16
#define SLICE_J 512     // 4 j-tiles of 128 per block
#define LDA 72          // padded LDS row stride (shorts)
#define TAU 0.10f       // candidate threshold; repair kernel guarantees exactness
#define CAPL 24         // per-row per-block LDS candidate cap
#define CAPG 192        // per-row global candidate cap

typedef float f32x4 __attribute__((ext_vector_type(4)));
typedef short bf16x8 __attribute__((ext_vector_type(8)));

__device__ __forceinline__ unsigned int bf16_bits_rne(float v) {
    unsigned int u = __float_as_uint(v);
    u += 0x7FFFu + ((u >> 16) & 1u);
    return u >> 16;
}

// ---------------- Kernel 0: row norms + bf16 normalized copy ----------------
__global__ __launch_bounds__(256) void norm_kernel(const float* __restrict__ h,
                                                   __hip_bfloat16* __restrict__ hn) {
    int row = blockIdx.x * 4 + (threadIdx.x >> 6);
    int lane = threadIdx.x & 63;
    const float* hr = h + (size_t)row * D;
    float v[8];
    float ss = 0.f;
#pragma unroll
    for (int e = 0; e < 8; e++) { v[e] = hr[lane + 64 * e]; ss += v[e] * v[e]; }
#pragma unroll
    for (int off = 32; off > 0; off >>= 1) ss += __shfl_xor(ss, off, 64);
    float inv = 1.0f / fmaxf(sqrtf(ss), EPS);
    __hip_bfloat16* hw = hn + (size_t)row * D;
#pragma unroll
    for (int e = 0; e < 8; e++) hw[lane + 64 * e] = __float2bfloat16(v[e] * inv);
}

// ------- Kernel 1: MFMA sim tiles + threshold-filter from registers -------
// grid (64, 16): i-tile of 128 rows x j-slice of 512 cols (4 tiles of 128)
__global__ __launch_bounds__(256, 3) void simthresh_kernel(
        const unsigned short* __restrict__ hn,
        unsigned int* __restrict__ gcand,
        int* __restrict__ gcnt,
        int* __restrict__ gflag) {
    __shared__ unsigned short Asm[128][LDA];
    __shared__ unsigned short Bsm[128][LDA];
    __shared__ int cnt[128];
    __shared__ unsigned int lbuf[128][CAPL];

    const int i0 = blockIdx.x * 128;
    const int sl = blockIdx.y;
    const int t = threadIdx.x;
    const int wave = t >> 6, lane = t & 63;
    const int wr = (wave >> 1) * 64, wc = (wave & 1) * 64;
    const int lm = lane & 15, lg = lane >> 4;

    if (t < 128) cnt[t] = 0;   // first staging barrier makes this visible

    for (int jt = 0; jt < 4; jt++) {
        const int j0 = sl * SLICE_J + jt * 128;
        f32x4 acc[4][4];
#pragma unroll
        for (int x = 0; x < 4; x++)
#pragma unroll
            for (int y = 0; y < 4; y++) acc[x][y] = (f32x4){0.f, 0.f, 0.f, 0.f};

        for (int ks = 0; ks < 8; ks++) {
            const int k0 = ks * 64;
            __syncthreads();
#pragma unroll
            for (int e = 0; e < 4; e++) {
                int lin = t + 256 * e;        // 128x64 tile as 16B chunks
                int r = lin >> 3;
                int c = (lin & 7) * 8;
                *(uint4*)(&Asm[r][c]) = *(const uint4*)(hn + (size_t)(i0 + r) * D + k0 + c);
                *(uint4*)(&Bsm[r][c]) = *(const uint4*)(hn + (size_t)(j0 + r) * D + k0 + c);
            }
            __syncthreads();
#pragma unroll
            for (int kk = 0; kk < 64; kk += 32) {
                bf16x8 af[4], bfr[4];
#pragma unroll
                for (int x = 0; x < 4; x++) {
                    af[x] = *(const bf16x8*)(&Asm[wr + x * 16 + lm][kk + lg * 8]);
                    bfr[x] = *(const bf16x8*)(&Bsm[wc + x * 16 + lm][kk + lg * 8]);
                }
#pragma unroll
                for (int x = 0; x < 4; x++)
#pragma unroll
                    for (int y = 0; y < 4; y++)
                        acc[x][y] = __builtin_amdgcn_mfma_f32_16x16x32_bf16(
                            af[x], bfr[y], acc[x][y], 0, 0, 0);
            }
        }
        // threshold-filter straight from accumulator registers (no barrier
        // needed: lbuf/cnt are disjoint from the staging buffers)
#pragma unroll
        for (int x = 0; x < 4; x++)
#pragma unroll
            for (int y = 0; y < 4; y++) {
                int gcol = j0 + wc + y * 16 + lm;
#pragma unroll
                for (int r = 0; r < 4; r++) {
                    // C/D row = wr (wave row-half) + x*16 (tile) + (lane>>4)*4 + reg
                    int row = wr + x * 16 + lg * 4 + r;   // FIX: wr was missing
                    float v = acc[x][y][r];
                    if (i0 + row == gcol) v = 1.0f;   // exact self-similarity
                    if (v > TAU) {
                        unsigned int e = (bf16_bits_rne(v) << 16) | (unsigned int)gcol;
                        int idx = atomicAdd(&cnt[row], 1);
                        if (idx < CAPL) lbuf[row][idx] = e;
                    }
                }
            }
    }
    __syncthreads();
    if (t < 128) {
        int c = cnt[t];
        int store = c < CAPL ? c : CAPL;
        if (c > 0) {
            int base = atomicAdd(&gcnt[i0 + t], c);
            unsigned int* dst = gcand + (size_t)(i0 + t) * CAPG;
            for (int k = 0; k < store; k++) {
                int p = base + k;
                if (p < CAPG) dst[p] = lbuf[t][k];
            }
        }
        if (c > CAPL) gflag[i0 + t] = 1;   // dropped candidates -> repair
    }
}

// ---- Kernel 2: repair (exactness guarantee; early-exits on healthy rows) ----
__global__ __launch_bounds__(64) void repair_kernel(const unsigned short* __restrict__ hn,
                                                    unsigned int* __restrict__ gcand,
                                                    int* __restrict__ gcnt,
                                                    const int* __restrict__ gflag) {
    int row = blockIdx.x;
    int c = gcnt[row];
    if (c >= K_TOP && c <= CAPG && gflag[row] == 0) return;

    int lane = threadIdx.x;
    float vals[K_TOP];
    int idxs[K_TOP];
#pragma unroll
    for (int q = 0; q < K_TOP; q++) { vals[q] = -3e38f; idxs[q] = 0; }
    float minv = -3e38f;
    int minp = 0;
    for (int col = lane; col < N; col += 64) {
        float s = 0.f;
        for (int k = 0; k < D; k++) {
            float a = __uint_as_float((unsigned int)hn[(size_t)row * D + k] << 16);
            float b = __uint_as_float((unsigned int)hn[(size_t)col * D + k] << 16);
            s += a * b;
        }
        if (col == row) s = 1.0f;
        if (s > minv) {
            vals[minp] = s; idxs[minp] = col;
            minv = vals[0]; minp = 0;
#pragma unroll
            for (int q = 1; q < K_TOP; q++)
                if (vals[q] < minv) { minv = vals[q]; minp = q; }
        }
    }
    float selv[K_TOP];
    int selj[K_TOP];
    for (int k = 0; k < K_TOP; k++) {
        float bv = vals[0]; int bp = 0;
#pragma unroll
        for (int q = 1; q < K_TOP; q++)
            if (vals[q] > bv) { bv = vals[q]; bp = q; }
        float v = bv; int j = idxs[bp]; int src = lane;
#pragma unroll
        for (int off = 32; off > 0; off >>= 1) {
            float ov = __shfl_xor(v, off, 64);
            int oj = __shfl_xor(j, off, 64);
            int os = __shfl_xor(src, off, 64);
            if (ov > v || (ov == v && os < src)) { v = ov; j = oj; src = os; }
        }
        selv[k] = v; selj[k] = j;
        if (lane == src) vals[bp] = -3e38f;
    }
    if (lane == 0) {
        unsigned int* dst = gcand + (size_t)row * CAPG;
        for (int k = 0; k < K_TOP; k++)
            dst[k] = (bf16_bits_rne(selv[k]) << 16) | (unsigned int)selj[k];
        gcnt[row] = K_TOP;
    }
}

// ------- Kernel 3: exact top-12 of candidates, softmax, weighted gather -------
__global__ __launch_bounds__(256) void gather_kernel(const float* __restrict__ h,
                                                     const unsigned int* __restrict__ gcand,
                                                     const int* __restrict__ gcnt,
                                                     float* __restrict__ out) {
    int row = blockIdx.x * 4 + (threadIdx.x >> 6);
    int lane = threadIdx.x & 63;
    int c = gcnt[row];
    if (c > CAPG) c = CAPG;
    const unsigned int* cr = gcand + (size_t)row * CAPG;
    unsigned int e[3];
#pragma unroll
    for (int q = 0; q < 3; q++) {
        int idx = lane + 64 * q;
        e[q] = (idx < c) ? cr[idx] : 0u;
    }
    float selv[K_TOP];
    int selj[K_TOP];
#pragma unroll
    for (int k = 0; k < K_TOP; k++) {
        unsigned int m = e[0];
        if (e[1] > m) m = e[1];
        if (e[2] > m) m = e[2];
#pragma unroll
        for (int off = 32; off > 0; off >>= 1) {
            unsigned int om = __shfl_xor(m, off, 64);
            if (om > m) m = om;
        }
        selv[k] = __uint_as_float(m & 0xFFFF0000u);
        selj[k] = (int)(m & 0x1FFFu);
#pragma unroll
        for (int q = 0; q < 3; q++)
            if (e[q] == m) e[q] = 0u;   // entries are unique (distinct cols)
    }
    float mx = selv[0];
    float beta[K_TOP];
    float sum = 0.f;
#pragma unroll
    for (int q = 0; q < K_TOP; q++) { beta[q] = __expf(THETA * (selv[q] - mx)); sum += beta[q]; }
    float rs = 1.0f / sum;

    float acc[8];
#pragma unroll
    for (int ee = 0; ee < 8; ee++) acc[ee] = 0.f;
#pragma unroll
    for (int q = 0; q < K_TOP; q++) {
        const float* hr = h + (size_t)selj[q] * D;
        float b = beta[q] * rs;
#pragma unroll
        for (int ee = 0; ee < 8; ee++) acc[ee] += b * hr[lane + 64 * ee];
    }
    float* orow = out + (size_t)row * D;
#pragma unroll
    for (int ee = 0; ee < 8; ee++) orow[lane + 64 * ee] = acc[ee];
}

extern "C" void kernel_launch(void* const* d_in, const int* in_sizes, int n_in,
                              void* d_out, int out_size, void* d_ws, size_t ws_size,
                              hipStream_t stream) {
    const float* h = (const float*)d_in[0];
    float* out = (float*)d_out;

    char* ws = (char*)d_ws;
    __hip_bfloat16* hn = (__hip_bfloat16*)ws;                    // 8 MB
    size_t off = (size_t)N * D * sizeof(__hip_bfloat16);
    int* gcnt = (int*)(ws + off);                                // 32 KB
    int* gflag = (int*)(ws + off + (size_t)N * 4);               // 32 KB
    unsigned int* gcand = (unsigned int*)(ws + off + (size_t)N * 8);  // 6 MB

    norm_kernel<<<N / 4, 256, 0, stream>>>(h, hn);
    hipMemsetAsync(gcnt, 0, (size_t)N * 8, stream);  // zeroes gcnt + gflag
    dim3 grid(64, NSLICE);
    simthresh_kernel<<<grid, 256, 0, stream>>>((const unsigned short*)hn, gcand, gcnt, gflag);
    repair_kernel<<<N, 64, 0, stream>>>((const unsigned short*)hn, gcand, gcnt, gflag);
    gather_kernel<<<N / 4, 256, 0, stream>>>(h, gcand, gcnt, out);
}

// Round 4
// 236.312 us; speedup vs baseline: 2.5479x; 1.2810x over previous
//
#include <hip/hip_runtime.h>
#include <hip/hip_bf16.h>

#define N 8192
#define D 512
#define K_TOP 12
#define THETA 10.0f
#define EPS 1e-8f
#define NSLICE 16
#define SLICE_J 512     // 4 j-tiles of 128 per block
#define TAU 0.10f       // candidate threshold; repair kernel guarantees exactness
#define CAPL 24         // per-row per-block LDS candidate cap
#define CAPG 192        // per-row global candidate cap

typedef float f32x4 __attribute__((ext_vector_type(4)));
typedef short bf16x8 __attribute__((ext_vector_type(8)));

__device__ __forceinline__ unsigned int bf16_bits_rne(float v) {
    unsigned int u = __float_as_uint(v);
    u += 0x7FFFu + ((u >> 16) & 1u);
    return u >> 16;
}

// async global->LDS DMA, 16B per lane; LDS dest is wave-uniform base + lane*16
__device__ __forceinline__ void load16(const unsigned short* g, unsigned short* l) {
    __builtin_amdgcn_global_load_lds(
        (const __attribute__((address_space(1))) unsigned int*)g,
        (__attribute__((address_space(3))) unsigned int*)l, 16, 0, 0);
}

// ---------------- Kernel 0: row norms + bf16 normalized copy ----------------
__global__ __launch_bounds__(256) void norm_kernel(const float* __restrict__ h,
                                                   __hip_bfloat16* __restrict__ hn) {
    int row = blockIdx.x * 4 + (threadIdx.x >> 6);
    int lane = threadIdx.x & 63;
    const float* hr = h + (size_t)row * D;
    float v[8];
    float ss = 0.f;
#pragma unroll
    for (int e = 0; e < 8; e++) { v[e] = hr[lane + 64 * e]; ss += v[e] * v[e]; }
#pragma unroll
    for (int off = 32; off > 0; off >>= 1) ss += __shfl_xor(ss, off, 64);
    float inv = 1.0f / fmaxf(sqrtf(ss), EPS);
    __hip_bfloat16* hw = hn + (size_t)row * D;
#pragma unroll
    for (int e = 0; e < 8; e++) hw[lane + 64 * e] = __float2bfloat16(v[e] * inv);
}

// ------- Kernel 1: MFMA sim tiles + threshold-filter from registers -------
// grid (64, 16): i-tile of 128 rows x j-slice of 512 cols (4 tiles of 128).
// Staging: global_load_lds dwordx4 into unpadded 128x64 tiles, XOR-swizzled:
// 16B chunk q of row r lives at slot q^(r&7). Fragment ds_read_b128 then hits
// all 32 banks across lm=0..7 (2-way residual = free).
__global__ __launch_bounds__(256, 3) void simthresh_kernel(
        const unsigned short* __restrict__ hn,
        unsigned int* __restrict__ gcand,
        int* __restrict__ gcnt,
        int* __restrict__ gflag) {
    __shared__ unsigned short Asm[128 * 64];
    __shared__ unsigned short Bsm[128 * 64];
    __shared__ int cnt[128];
    __shared__ unsigned int lbuf[128][CAPL];

    const int i0 = blockIdx.x * 128;
    const int sl = blockIdx.y;
    const int t = threadIdx.x;
    const int wave = t >> 6, lane = t & 63;
    const int wr = (wave >> 1) * 64, wc = (wave & 1) * 64;
    const int lm = lane & 15, lg = lane >> 4;

    // staging geometry: LDS chunk index c = e*256 + t  (e=0..3)
    //   row r = c>>3 = (t>>3) + e*32,  slot-in-row = t&7,
    //   source chunk q = (t&7) ^ (r&7); r&7 == (t>>3)&7 (e*32 ≡ 0 mod 8)
    const int srow = t >> 3;
    const int sq = (t & 7) ^ (srow & 7);
    const int cb = lm & 7;  // read-side swizzle key

    if (t < 128) cnt[t] = 0;   // first staging barrier publishes this

    for (int jt = 0; jt < 4; jt++) {
        const int j0 = sl * SLICE_J + jt * 128;
        f32x4 acc[4][4];
#pragma unroll
        for (int x = 0; x < 4; x++)
#pragma unroll
            for (int y = 0; y < 4; y++) acc[x][y] = (f32x4){0.f, 0.f, 0.f, 0.f};

        for (int ks = 0; ks < 8; ks++) {
            const int k0 = ks * 64;
            __syncthreads();   // prior LDS reads done before DMA overwrites
            const unsigned short* gA = hn + (size_t)(i0 + srow) * D + k0 + sq * 8;
            const unsigned short* gB = hn + (size_t)(j0 + srow) * D + k0 + sq * 8;
#pragma unroll
            for (int e = 0; e < 4; e++) {
                load16(gA + (size_t)(e * 32) * D, &Asm[(e * 256 + t) * 8]);
                load16(gB + (size_t)(e * 32) * D, &Bsm[(e * 256 + t) * 8]);
            }
            __syncthreads();   // compiler drains vmcnt(0) before barrier
#pragma unroll
            for (int kk = 0; kk < 64; kk += 32) {
                const int csw = ((kk >> 3) + lg) ^ cb;  // swizzled chunk index
                bf16x8 af[4], bfr[4];
#pragma unroll
                for (int x = 0; x < 4; x++) {
                    af[x] = *(const bf16x8*)&Asm[(wr + x * 16 + lm) * 64 + csw * 8];
                    bfr[x] = *(const bf16x8*)&Bsm[(wc + x * 16 + lm) * 64 + csw * 8];
                }
#pragma unroll
                for (int x = 0; x < 4; x++)
#pragma unroll
                    for (int y = 0; y < 4; y++)
                        acc[x][y] = __builtin_amdgcn_mfma_f32_16x16x32_bf16(
                            af[x], bfr[y], acc[x][y], 0, 0, 0);
            }
        }
        // threshold-filter straight from accumulator registers
#pragma unroll
        for (int x = 0; x < 4; x++)
#pragma unroll
            for (int y = 0; y < 4; y++) {
                int gcol = j0 + wc + y * 16 + lm;
#pragma unroll
                for (int r = 0; r < 4; r++) {
                    int row = wr + x * 16 + lg * 4 + r;  // C/D row incl. wave half
                    float v = acc[x][y][r];
                    if (i0 + row == gcol) v = 1.0f;      // exact self-similarity
                    if (v > TAU) {
                        unsigned int e = (bf16_bits_rne(v) << 16) | (unsigned int)gcol;
                        int idx = atomicAdd(&cnt[row], 1);
                        if (idx < CAPL) lbuf[row][idx] = e;
                    }
                }
            }
    }
    __syncthreads();
    if (t < 128) {
        int c = cnt[t];
        int store = c < CAPL ? c : CAPL;
        if (c > 0) {
            int base = atomicAdd(&gcnt[i0 + t], c);
            unsigned int* dst = gcand + (size_t)(i0 + t) * CAPG;
            for (int k = 0; k < store; k++) {
                int p = base + k;
                if (p < CAPG) dst[p] = lbuf[t][k];
            }
        }
        if (c > CAPL) gflag[i0 + t] = 1;   // dropped candidates -> repair
    }
}

// ---- Kernel 2: repair (exactness guarantee; early-exits on healthy rows) ----
__global__ __launch_bounds__(64) void repair_kernel(const unsigned short* __restrict__ hn,
                                                    unsigned int* __restrict__ gcand,
                                                    int* __restrict__ gcnt,
                                                    const int* __restrict__ gflag) {
    int row = blockIdx.x;
    int c = gcnt[row];
    if (c >= K_TOP && c <= CAPG && gflag[row] == 0) return;

    int lane = threadIdx.x;
    float vals[K_TOP];
    int idxs[K_TOP];
#pragma unroll
    for (int q = 0; q < K_TOP; q++) { vals[q] = -3e38f; idxs[q] = 0; }
    float minv = -3e38f;
    int minp = 0;
    for (int col = lane; col < N; col += 64) {
        float s = 0.f;
        for (int k = 0; k < D; k++) {
            float a = __uint_as_float((unsigned int)hn[(size_t)row * D + k] << 16);
            float b = __uint_as_float((unsigned int)hn[(size_t)col * D + k] << 16);
            s += a * b;
        }
        if (col == row) s = 1.0f;
        if (s > minv) {
            vals[minp] = s; idxs[minp] = col;
            minv = vals[0]; minp = 0;
#pragma unroll
            for (int q = 1; q < K_TOP; q++)
                if (vals[q] < minv) { minv = vals[q]; minp = q; }
        }
    }
    float selv[K_TOP];
    int selj[K_TOP];
    for (int k = 0; k < K_TOP; k++) {
        float bv = vals[0]; int bp = 0;
#pragma unroll
        for (int q = 1; q < K_TOP; q++)
            if (vals[q] > bv) { bv = vals[q]; bp = q; }
        float v = bv; int j = idxs[bp]; int src = lane;
#pragma unroll
        for (int off = 32; off > 0; off >>= 1) {
            float ov = __shfl_xor(v, off, 64);
            int oj = __shfl_xor(j, off, 64);
            int os = __shfl_xor(src, off, 64);
            if (ov > v || (ov == v && os < src)) { v = ov; j = oj; src = os; }
        }
        selv[k] = v; selj[k] = j;
        if (lane == src) vals[bp] = -3e38f;
    }
    if (lane == 0) {
        unsigned int* dst = gcand + (size_t)row * CAPG;
        for (int k = 0; k < K_TOP; k++)
            dst[k] = (bf16_bits_rne(selv[k]) << 16) | (unsigned int)selj[k];
        gcnt[row] = K_TOP;
    }
}

// ------- Kernel 3: exact top-12 of candidates, softmax, weighted gather -------
__global__ __launch_bounds__(256) void gather_kernel(const float* __restrict__ h,
                                                     const unsigned int* __restrict__ gcand,
                                                     const int* __restrict__ gcnt,
                                                     float* __restrict__ out) {
    int row = blockIdx.x * 4 + (threadIdx.x >> 6);
    int lane = threadIdx.x & 63;
    int c = gcnt[row];
    if (c > CAPG) c = CAPG;
    const unsigned int* cr = gcand + (size_t)row * CAPG;
    unsigned int e[3];
#pragma unroll
    for (int q = 0; q < 3; q++) {
        int idx = lane + 64 * q;
        e[q] = (idx < c) ? cr[idx] : 0u;
    }
    float selv[K_TOP];
    int selj[K_TOP];
#pragma unroll
    for (int k = 0; k < K_TOP; k++) {
        unsigned int m = e[0];
        if (e[1] > m) m = e[1];
        if (e[2] > m) m = e[2];
#pragma unroll
        for (int off = 32; off > 0; off >>= 1) {
            unsigned int om = __shfl_xor(m, off, 64);
            if (om > m) m = om;
        }
        selv[k] = __uint_as_float(m & 0xFFFF0000u);
        selj[k] = (int)(m & 0x1FFFu);
#pragma unroll
        for (int q = 0; q < 3; q++)
            if (e[q] == m) e[q] = 0u;   // entries are unique (distinct cols)
    }
    float mx = selv[0];
    float beta[K_TOP];
    float sum = 0.f;
#pragma unroll
    for (int q = 0; q < K_TOP; q++) { beta[q] = __expf(THETA * (selv[q] - mx)); sum += beta[q]; }
    float rs = 1.0f / sum;

    float acc[8];
#pragma unroll
    for (int ee = 0; ee < 8; ee++) acc[ee] = 0.f;
#pragma unroll
    for (int q = 0; q < K_TOP; q++) {
        const float* hr = h + (size_t)selj[q] * D;
        float b = beta[q] * rs;
#pragma unroll
        for (int ee = 0; ee < 8; ee++) acc[ee] += b * hr[lane + 64 * ee];
    }
    float* orow = out + (size_t)row * D;
#pragma unroll
    for (int ee = 0; ee < 8; ee++) orow[lane + 64 * ee] = acc[ee];
}

extern "C" void kernel_launch(void* const* d_in, const int* in_sizes, int n_in,
                              void* d_out, int out_size, void* d_ws, size_t ws_size,
                              hipStream_t stream) {
    const float* h = (const float*)d_in[0];
    float* out = (float*)d_out;

    char* ws = (char*)d_ws;
    __hip_bfloat16* hn = (__hip_bfloat16*)ws;                    // 8 MB
    size_t off = (size_t)N * D * sizeof(__hip_bfloat16);
    int* gcnt = (int*)(ws + off);                                // 32 KB
    int* gflag = (int*)(ws + off + (size_t)N * 4);               // 32 KB
    unsigned int* gcand = (unsigned int*)(ws + off + (size_t)N * 8);  // 6 MB

    norm_kernel<<<N / 4, 256, 0, stream>>>(h, hn);
    hipMemsetAsync(gcnt, 0, (size_t)N * 8, stream);  // zeroes gcnt + gflag
    dim3 grid(64, NSLICE);
    simthresh_kernel<<<grid, 256, 0, stream>>>((const unsigned short*)hn, gcand, gcnt, gflag);
    repair_kernel<<<N, 64, 0, stream>>>((const unsigned short*)hn, gcand, gcnt, gflag);
    gather_kernel<<<N / 4, 256, 0, stream>>>(h, gcand, gcnt, out);
}

// Round 5
// 202.119 us; speedup vs baseline: 2.9789x; 1.1692x over previous
//
#include <hip/hip_runtime.h>
#include <hip/hip_bf16.h>

#define N 8192
#define D 512
#define K_TOP 12
#define THETA 10.0f
#define EPS 1e-8f
#define NSLICE 16
#define SLICE_J 512     // 4 j-tiles of 128 per block
#define TAU 0.10f       // candidate threshold; gather fallback guarantees exactness
#define CAPL 24         // per-row per-block LDS candidate cap
#define CAPG 192        // per-row global candidate cap
#define NROUND 32       // 4 jt x 8 ks staging rounds

typedef float f32x16 __attribute__((ext_vector_type(16)));
typedef short bf16x8 __attribute__((ext_vector_type(8)));

__device__ __forceinline__ unsigned int bf16_bits_rne(float v) {
    unsigned int u = __float_as_uint(v);
    u += 0x7FFFu + ((u >> 16) & 1u);
    return u >> 16;
}

// async global->LDS DMA, 16B per lane; LDS dest is wave-uniform base + lane*16
__device__ __forceinline__ void load16(const unsigned short* g, unsigned short* l) {
    __builtin_amdgcn_global_load_lds(
        (const __attribute__((address_space(1))) unsigned int*)g,
        (__attribute__((address_space(3))) unsigned int*)l, 16, 0, 0);
}

// ------ Kernel 0: row norms + bf16 normalized copy + zero gcnt/gflag ------
__global__ __launch_bounds__(256) void norm_kernel(const float* __restrict__ h,
                                                   __hip_bfloat16* __restrict__ hn,
                                                   int* __restrict__ gcnt,
                                                   int* __restrict__ gflag) {
    int row = blockIdx.x * 4 + (threadIdx.x >> 6);
    int lane = threadIdx.x & 63;
    if (lane == 0) { gcnt[row] = 0; gflag[row] = 0; }
    const float* hr = h + (size_t)row * D;
    float v[8];
    float ss = 0.f;
#pragma unroll
    for (int e = 0; e < 8; e++) { v[e] = hr[lane + 64 * e]; ss += v[e] * v[e]; }
#pragma unroll
    for (int off = 32; off > 0; off >>= 1) ss += __shfl_xor(ss, off, 64);
    float inv = 1.0f / fmaxf(sqrtf(ss), EPS);
    __hip_bfloat16* hw = hn + (size_t)row * D;
#pragma unroll
    for (int e = 0; e < 8; e++) hw[lane + 64 * e] = __float2bfloat16(v[e] * inv);
}

// ------- Kernel 1: pipelined MFMA sim tiles + threshold-filter -------
// grid (64, 16). Double-buffered 128x64 XOR-swizzled tiles, global_load_lds
// prefetch one round ahead, raw s_waitcnt vmcnt(8) + s_barrier (AITER-style).
// MFMA 32x32x16: per wave 2x2 accs over its 64x64 quadrant.
__global__ __launch_bounds__(256, 2) void simthresh_kernel(
        const unsigned short* __restrict__ hn,
        unsigned int* __restrict__ gcand,
        int* __restrict__ gcnt,
        int* __restrict__ gflag) {
    __shared__ unsigned short tiles[2][2][128 * 64];  // [sel][A/B][tile]
    __shared__ int cnt[128];
    __shared__ unsigned int lbuf[128][CAPL];

    const int i0 = blockIdx.x * 128;
    const int sl = blockIdx.y;
    const int t = threadIdx.x;
    const int wave = t >> 6, lane = t & 63;
    const int wr = (wave >> 1) * 64, wc = (wave & 1) * 64;
    const int lm32 = lane & 31, lg2 = lane >> 5;
    const int cb = lm32 & 7;  // read-side swizzle key

    // staging geometry: chunk c = e*256 + t; row = c>>3, slot = t&7,
    // source chunk q = (t&7) ^ (row&7); row&7 == (t>>3)&7
    const int srow = t >> 3;
    const int sq = (t & 7) ^ (srow & 7);

    if (t < 128) cnt[t] = 0;   // published by first barrier pair

    auto issue = [&](int r, int sel) {
        int jt = r >> 3, ks = r & 7;
        int j0 = sl * SLICE_J + jt * 128;
        int k0 = ks * 64;
        const unsigned short* gA = hn + (size_t)(i0 + srow) * D + k0 + sq * 8;
        const unsigned short* gB = hn + (size_t)(j0 + srow) * D + k0 + sq * 8;
        unsigned short* lA = &tiles[sel][0][t * 8];
        unsigned short* lB = &tiles[sel][1][t * 8];
#pragma unroll
        for (int e = 0; e < 4; e++) {
            load16(gA + (size_t)(e * 32) * D, lA + e * 2048);
            load16(gB + (size_t)(e * 32) * D, lB + e * 2048);
        }
    };

    issue(0, 0);
    f32x16 acc[2][2];

    for (int r = 0; r < NROUND; r++) {
        const int sel = r & 1;
        const int jt = r >> 3, ks = r & 7;
        const int j0 = sl * SLICE_J + jt * 128;

        __builtin_amdgcn_s_barrier();   // all waves done computing round r-1
        if (r < NROUND - 1) {
            issue(r + 1, sel ^ 1);
            asm volatile("s_waitcnt vmcnt(8)" ::: "memory");  // drain round r only
        } else {
            asm volatile("s_waitcnt vmcnt(0)" ::: "memory");
        }
        __builtin_amdgcn_s_barrier();   // everyone's round-r loads are in LDS

        if (ks == 0) {
#pragma unroll
            for (int x = 0; x < 2; x++)
#pragma unroll
                for (int y = 0; y < 2; y++)
#pragma unroll
                    for (int q = 0; q < 16; q++) acc[x][y][q] = 0.f;
        }
#pragma unroll
        for (int kk = 0; kk < 64; kk += 16) {
            const int csw = ((kk >> 3) + lg2) ^ cb;
            bf16x8 af[2], bfr[2];
#pragma unroll
            for (int x = 0; x < 2; x++)
                af[x] = *(const bf16x8*)&tiles[sel][0][(wr + x * 32 + lm32) * 64 + csw * 8];
#pragma unroll
            for (int y = 0; y < 2; y++)
                bfr[y] = *(const bf16x8*)&tiles[sel][1][(wc + y * 32 + lm32) * 64 + csw * 8];
#pragma unroll
            for (int x = 0; x < 2; x++)
#pragma unroll
                for (int y = 0; y < 2; y++)
                    acc[x][y] = __builtin_amdgcn_mfma_f32_32x32x16_bf16(
                        af[x], bfr[y], acc[x][y], 0, 0, 0);
        }

        if (ks == 7) {
            // filter from regs; 32x32 C/D: col=lane&31, row=(reg&3)+8*(reg>>2)+4*(lane>>5)
#pragma unroll
            for (int x = 0; x < 2; x++)
#pragma unroll
                for (int y = 0; y < 2; y++) {
                    int gcol = j0 + wc + y * 32 + lm32;
#pragma unroll
                    for (int q = 0; q < 16; q++) {
                        int row = wr + x * 32 + (q & 3) + 8 * (q >> 2) + 4 * lg2;
                        float v = acc[x][y][q];
                        if (i0 + row == gcol) v = 1.0f;   // exact self-similarity
                        if (v > TAU) {
                            unsigned int e = (bf16_bits_rne(v) << 16) | (unsigned int)gcol;
                            int idx = atomicAdd(&cnt[row], 1);
                            if (idx < CAPL) lbuf[row][idx] = e;
                        }
                    }
                }
        }
    }
    __syncthreads();
    if (t < 128) {
        int c = cnt[t];
        int store = c < CAPL ? c : CAPL;
        if (c > 0) {
            int base = atomicAdd(&gcnt[i0 + t], c);
            unsigned int* dst = gcand + (size_t)(i0 + t) * CAPG;
            for (int k = 0; k < store; k++) {
                int p = base + k;
                if (p < CAPG) dst[p] = lbuf[t][k];
            }
        }
        if (c > CAPL) gflag[i0 + t] = 1;   // dropped candidates -> fallback
    }
}

// ---- Kernel 2: exact top-12 + softmax + gather, with brute-force fallback ----
__global__ __launch_bounds__(256) void gather_kernel(const float* __restrict__ h,
                                                     const unsigned short* __restrict__ hn,
                                                     const unsigned int* __restrict__ gcand,
                                                     const int* __restrict__ gcnt,
                                                     const int* __restrict__ gflag,
                                                     float* __restrict__ out) {
    int row = blockIdx.x * 4 + (threadIdx.x >> 6);
    int lane = threadIdx.x & 63;
    int c = gcnt[row];

    float selv[K_TOP];
    int selj[K_TOP];

    if (c >= K_TOP && c <= CAPG && gflag[row] == 0) {
        // normal path: exact top-12 of the ~97 thresholded candidates
        const unsigned int* cr = gcand + (size_t)row * CAPG;
        unsigned int e[3];
#pragma unroll
        for (int q = 0; q < 3; q++) {
            int idx = lane + 64 * q;
            e[q] = (idx < c) ? cr[idx] : 0u;
        }
#pragma unroll
        for (int k = 0; k < K_TOP; k++) {
            unsigned int m = e[0];
            if (e[1] > m) m = e[1];
            if (e[2] > m) m = e[2];
#pragma unroll
            for (int off = 32; off > 0; off >>= 1) {
                unsigned int om = __shfl_xor(m, off, 64);
                if (om > m) m = om;
            }
            selv[k] = __uint_as_float(m & 0xFFFF0000u);
            selj[k] = (int)(m & 0x1FFFu);
#pragma unroll
            for (int q = 0; q < 3; q++)
                if (e[q] == m) e[q] = 0u;   // entries unique (distinct cols)
        }
    } else {
        // fallback: exact brute-force top-12 (never fires on this data)
        float vals[K_TOP];
        int idxs[K_TOP];
#pragma unroll
        for (int q = 0; q < K_TOP; q++) { vals[q] = -3e38f; idxs[q] = 0; }
        float minv = -3e38f;
        int minp = 0;
        for (int col = lane; col < N; col += 64) {
            float s = 0.f;
            for (int k = 0; k < D; k++) {
                float a = __uint_as_float((unsigned int)hn[(size_t)row * D + k] << 16);
                float b = __uint_as_float((unsigned int)hn[(size_t)col * D + k] << 16);
                s += a * b;
            }
            if (col == row) s = 1.0f;
            if (s > minv) {
                vals[minp] = s; idxs[minp] = col;
                minv = vals[0]; minp = 0;
#pragma unroll
                for (int q = 1; q < K_TOP; q++)
                    if (vals[q] < minv) { minv = vals[q]; minp = q; }
            }
        }
        for (int k = 0; k < K_TOP; k++) {
            float bv = vals[0]; int bp = 0;
#pragma unroll
            for (int q = 1; q < K_TOP; q++)
                if (vals[q] > bv) { bv = vals[q]; bp = q; }
            float v = bv; int j = idxs[bp]; int src = lane;
#pragma unroll
            for (int off = 32; off > 0; off >>= 1) {
                float ov = __shfl_xor(v, off, 64);
                int oj = __shfl_xor(j, off, 64);
                int os = __shfl_xor(src, off, 64);
                if (ov > v || (ov == v && os < src)) { v = ov; j = oj; src = os; }
            }
            selv[k] = bf16_bits_rne(v) ? __uint_as_float(bf16_bits_rne(v) << 16) : 0.f;
            selj[k] = j;
            if (lane == src) vals[bp] = -3e38f;
        }
    }

    float mx = selv[0];
    float beta[K_TOP];
    float sum = 0.f;
#pragma unroll
    for (int q = 0; q < K_TOP; q++) { beta[q] = __expf(THETA * (selv[q] - mx)); sum += beta[q]; }
    float rs = 1.0f / sum;

    float acc[8];
#pragma unroll
    for (int ee = 0; ee < 8; ee++) acc[ee] = 0.f;
#pragma unroll
    for (int q = 0; q < K_TOP; q++) {
        const float* hr = h + (size_t)selj[q] * D;
        float b = beta[q] * rs;
#pragma unroll
        for (int ee = 0; ee < 8; ee++) acc[ee] += b * hr[lane + 64 * ee];
    }
    float* orow = out + (size_t)row * D;
#pragma unroll
    for (int ee = 0; ee < 8; ee++) orow[lane + 64 * ee] = acc[ee];
}

extern "C" void kernel_launch(void* const* d_in, const int* in_sizes, int n_in,
                              void* d_out, int out_size, void* d_ws, size_t ws_size,
                              hipStream_t stream) {
    const float* h = (const float*)d_in[0];
    float* out = (float*)d_out;

    char* ws = (char*)d_ws;
    __hip_bfloat16* hn = (__hip_bfloat16*)ws;                    // 8 MB
    size_t off = (size_t)N * D * sizeof(__hip_bfloat16);
    int* gcnt = (int*)(ws + off);                                // 32 KB
    int* gflag = (int*)(ws + off + (size_t)N * 4);               // 32 KB
    unsigned int* gcand = (unsigned int*)(ws + off + (size_t)N * 8);  // 6 MB

    norm_kernel<<<N / 4, 256, 0, stream>>>(h, hn, gcnt, gflag);
    dim3 grid(64, NSLICE);
    simthresh_kernel<<<grid, 256, 0, stream>>>((const unsigned short*)hn, gcand, gcnt, gflag);
    gather_kernel<<<N / 4, 256, 0, stream>>>(h, (const unsigned short*)hn, gcand, gcnt,
                                             gflag, out);
}

// Round 6
// 183.006 us; speedup vs baseline: 3.2900x; 1.1044x over previous
//
#include <hip/hip_runtime.h>
#include <hip/hip_bf16.h>

#define N 8192
#define D 512
#define NT 64          // number of 128-row tiles
#define K_TOP 12
#define THETA 10.0f
#define EPS 1e-8f
#define TAU 0.10f      // candidate threshold; spill+fallback guarantee exactness
#define CAPL 12        // per-row per-block LDS candidate cap (overflow -> global spill)
#define CAPG 192       // per-row global candidate cap
#define NROUND 8       // K=512 in 8 x 64 staging rounds

typedef float f32x16 __attribute__((ext_vector_type(16)));
typedef short bf16x8 __attribute__((ext_vector_type(8)));
typedef unsigned short u16x8 __attribute__((ext_vector_type(8)));

__device__ __forceinline__ unsigned int bf16_bits_rne(float v) {
    unsigned int u = __float_as_uint(v);
    u += 0x7FFFu + ((u >> 16) & 1u);
    return u >> 16;
}

// async global->LDS DMA, 16B per lane; LDS dest is wave-uniform base + lane*16
__device__ __forceinline__ void load16(const unsigned short* g, unsigned short* l) {
    __builtin_amdgcn_global_load_lds(
        (const __attribute__((address_space(1))) unsigned int*)g,
        (__attribute__((address_space(3))) unsigned int*)l, 16, 0, 0);
}

// -- Kernel 0: row norms, bf16 normalized copy, norm save, zero gcnt/gflag --
__global__ __launch_bounds__(256) void norm_kernel(const float* __restrict__ h,
                                                   __hip_bfloat16* __restrict__ hn,
                                                   float* __restrict__ norms,
                                                   int* __restrict__ gcnt,
                                                   int* __restrict__ gflag) {
    int row = blockIdx.x * 4 + (threadIdx.x >> 6);
    int lane = threadIdx.x & 63;
    const float* hr = h + (size_t)row * D;
    float v[8];
    float ss = 0.f;
#pragma unroll
    for (int e = 0; e < 8; e++) { v[e] = hr[lane + 64 * e]; ss += v[e] * v[e]; }
#pragma unroll
    for (int off = 32; off > 0; off >>= 1) ss += __shfl_xor(ss, off, 64);
    float nrm = fmaxf(sqrtf(ss), EPS);
    float inv = 1.0f / nrm;
    if (lane == 0) { gcnt[row] = 0; gflag[row] = 0; norms[row] = nrm; }
    __hip_bfloat16* hw = hn + (size_t)row * D;
#pragma unroll
    for (int e = 0; e < 8; e++) hw[lane + 64 * e] = __float2bfloat16(v[e] * inv);
}

// -- Kernel 1: symmetric MFMA tile-pairs + two-sided threshold filter --
// grid = 2080 upper-triangular (a,b) 128x128 tile-pairs. Double-buffered
// XOR-swizzled tiles, global_load_lds prefetch, raw vmcnt(8) + s_barrier.
// Each hit (i,j,v) appended to row i, and (off-diag) also to row j.
__global__ __launch_bounds__(256, 2) void simtri_kernel(
        const unsigned short* __restrict__ hn,
        unsigned int* __restrict__ gcand,
        int* __restrict__ gcnt,
        int* __restrict__ gflag) {
    __shared__ unsigned short tiles[2][2][128 * 64];  // [sel][A/B][tile] 64 KB
    __shared__ int cnt[128], jcnt[128];
    __shared__ unsigned int lbuf[128][CAPL], jbuf[128][CAPL];

    // decode triangular pair (a <= b)
    int rem = blockIdx.x, a = 0;
    while (rem >= NT - a) { rem -= NT - a; a++; }
    const int b = a + rem;
    const int i0 = a * 128, j0 = b * 128;
    const bool diag = (a == b);

    const int t = threadIdx.x;
    const int wave = t >> 6, lane = t & 63;
    const int wr = (wave >> 1) * 64, wc = (wave & 1) * 64;
    const int lm32 = lane & 31, lg2 = lane >> 5;
    const int cb = lm32 & 7;  // read-side swizzle key

    // staging geometry: chunk c = e*256 + t; row = c>>3, slot = t&7,
    // source chunk q = (t&7) ^ (row&7); row&7 == (t>>3)&7
    const int srow = t >> 3;
    const int sq = (t & 7) ^ (srow & 7);

    if (t < 128) { cnt[t] = 0; jcnt[t] = 0; }   // published by first barrier

    auto issue = [&](int r, int sel) {
        int k0 = r * 64;
        const unsigned short* gA = hn + (size_t)(i0 + srow) * D + k0 + sq * 8;
        const unsigned short* gB = hn + (size_t)(j0 + srow) * D + k0 + sq * 8;
        unsigned short* lA = &tiles[sel][0][t * 8];
        unsigned short* lB = &tiles[sel][1][t * 8];
#pragma unroll
        for (int e = 0; e < 4; e++) {
            load16(gA + (size_t)(e * 32) * D, lA + e * 2048);
            load16(gB + (size_t)(e * 32) * D, lB + e * 2048);
        }
    };

    issue(0, 0);
    f32x16 acc[2][2];
#pragma unroll
    for (int x = 0; x < 2; x++)
#pragma unroll
        for (int y = 0; y < 2; y++)
#pragma unroll
            for (int q = 0; q < 16; q++) acc[x][y][q] = 0.f;

    for (int r = 0; r < NROUND; r++) {
        const int sel = r & 1;
        __builtin_amdgcn_s_barrier();   // all waves done reading buffer sel
        if (r < NROUND - 1) {
            issue(r + 1, sel ^ 1);
            asm volatile("s_waitcnt vmcnt(8)" ::: "memory");  // drain round r only
        } else {
            asm volatile("s_waitcnt vmcnt(0)" ::: "memory");
        }
        __builtin_amdgcn_s_barrier();   // everyone's round-r loads are in LDS

#pragma unroll
        for (int kk = 0; kk < 64; kk += 16) {
            const int csw = ((kk >> 3) + lg2) ^ cb;
            bf16x8 af[2], bfr[2];
#pragma unroll
            for (int x = 0; x < 2; x++)
                af[x] = *(const bf16x8*)&tiles[sel][0][(wr + x * 32 + lm32) * 64 + csw * 8];
#pragma unroll
            for (int y = 0; y < 2; y++)
                bfr[y] = *(const bf16x8*)&tiles[sel][1][(wc + y * 32 + lm32) * 64 + csw * 8];
#pragma unroll
            for (int x = 0; x < 2; x++)
#pragma unroll
                for (int y = 0; y < 2; y++)
                    acc[x][y] = __builtin_amdgcn_mfma_f32_32x32x16_bf16(
                        af[x], bfr[y], acc[x][y], 0, 0, 0);
        }
    }

    // two-sided threshold filter from accumulator registers.
    // 32x32 C/D: col = lane&31, row = (reg&3) + 8*(reg>>2) + 4*(lane>>5)
    auto appendI = [&](int lr, unsigned int e) {
        int idx = atomicAdd(&cnt[lr], 1);
        if (idx < CAPL) lbuf[lr][idx] = e;
        else {  // rare spill: exact, straight to global
            int grow = i0 + lr;
            int p = atomicAdd(&gcnt[grow], 1);
            if (p < CAPG) gcand[(size_t)grow * CAPG + p] = e;
            else gflag[grow] = 1;
        }
    };
    auto appendJ = [&](int lr, unsigned int e) {
        int idx = atomicAdd(&jcnt[lr], 1);
        if (idx < CAPL) jbuf[lr][idx] = e;
        else {
            int grow = j0 + lr;
            int p = atomicAdd(&gcnt[grow], 1);
            if (p < CAPG) gcand[(size_t)grow * CAPG + p] = e;
            else gflag[grow] = 1;
        }
    };

#pragma unroll
    for (int x = 0; x < 2; x++)
#pragma unroll
        for (int y = 0; y < 2; y++) {
            int cl = wc + y * 32 + lm32;   // local j col
#pragma unroll
            for (int q = 0; q < 16; q++) {
                int rr = wr + x * 32 + (q & 3) + 8 * (q >> 2) + 4 * lg2;  // local i row
                float v = acc[x][y][q];
                if (diag) {
                    if (cl == rr) {
                        appendI(rr, (bf16_bits_rne(1.0f) << 16) | (unsigned int)(j0 + cl));
                    } else if (cl > rr && v > TAU) {
                        unsigned int vb = bf16_bits_rne(v) << 16;
                        appendI(rr, vb | (unsigned int)(j0 + cl));
                        appendI(cl, vb | (unsigned int)(i0 + rr));  // same tile rows
                    }
                } else if (v > TAU) {
                    unsigned int vb = bf16_bits_rne(v) << 16;
                    appendI(rr, vb | (unsigned int)(j0 + cl));
                    appendJ(cl, vb | (unsigned int)(i0 + rr));
                }
            }
        }

    __syncthreads();
    if (t < 128 || !diag) {
        int lr = t & 127;
        bool iside = t < 128;
        int c = iside ? cnt[lr] : jcnt[lr];
        int grow = (iside ? i0 : j0) + lr;
        const unsigned int* src = iside ? lbuf[lr] : jbuf[lr];
        int s = c < CAPL ? c : CAPL;      // spilled entries already in global
        if (s > 0) {
            int base = atomicAdd(&gcnt[grow], s);
            unsigned int* dst = gcand + (size_t)grow * CAPG;
            for (int k = 0; k < s; k++) {
                int p = base + k;
                if (p < CAPG) dst[p] = src[k];
                else gflag[grow] = 1;
            }
        }
    }
}

// -- Kernel 2: exact top-12 + softmax + gather (bf16 neighbors, fp32 self) --
__global__ __launch_bounds__(256) void gather_kernel(const float* __restrict__ h,
                                                     const unsigned short* __restrict__ hn,
                                                     const float* __restrict__ norms,
                                                     const unsigned int* __restrict__ gcand,
                                                     const int* __restrict__ gcnt,
                                                     const int* __restrict__ gflag,
                                                     float* __restrict__ out) {
    int row = blockIdx.x * 4 + (threadIdx.x >> 6);
    int lane = threadIdx.x & 63;
    int c = gcnt[row];

    float selv[K_TOP];
    int selj[K_TOP];

    if (c >= K_TOP && c <= CAPG && gflag[row] == 0) {
        const unsigned int* cr = gcand + (size_t)row * CAPG;
        unsigned int e[3];
#pragma unroll
        for (int q = 0; q < 3; q++) {
            int idx = lane + 64 * q;
            e[q] = (idx < c) ? cr[idx] : 0u;
        }
#pragma unroll
        for (int k = 0; k < K_TOP; k++) {
            unsigned int m = e[0];
            if (e[1] > m) m = e[1];
            if (e[2] > m) m = e[2];
#pragma unroll
            for (int off = 32; off > 0; off >>= 1) {
                unsigned int om = __shfl_xor(m, off, 64);
                if (om > m) m = om;
            }
            selv[k] = __uint_as_float(m & 0xFFFF0000u);
            selj[k] = (int)(m & 0x1FFFu);
#pragma unroll
            for (int q = 0; q < 3; q++)
                if (e[q] == m) e[q] = 0u;   // entries unique (distinct cols)
        }
    } else {
        // exact brute-force fallback (never fires on this data)
        float vals[K_TOP];
        int idxs[K_TOP];
#pragma unroll
        for (int q = 0; q < K_TOP; q++) { vals[q] = -3e38f; idxs[q] = 0; }
        float minv = -3e38f;
        int minp = 0;
        for (int col = lane; col < N; col += 64) {
            float s = 0.f;
            for (int k = 0; k < D; k++) {
                float av = __uint_as_float((unsigned int)hn[(size_t)row * D + k] << 16);
                float bv = __uint_as_float((unsigned int)hn[(size_t)col * D + k] << 16);
                s += av * bv;
            }
            if (col == row) s = 1.0f;
            if (s > minv) {
                vals[minp] = s; idxs[minp] = col;
                minv = vals[0]; minp = 0;
#pragma unroll
                for (int q = 1; q < K_TOP; q++)
                    if (vals[q] < minv) { minv = vals[q]; minp = q; }
            }
        }
        for (int k = 0; k < K_TOP; k++) {
            float bv = vals[0]; int bp = 0;
#pragma unroll
            for (int q = 1; q < K_TOP; q++)
                if (vals[q] > bv) { bv = vals[q]; bp = q; }
            float v = bv; int j = idxs[bp]; int src = lane;
#pragma unroll
            for (int off = 32; off > 0; off >>= 1) {
                float ov = __shfl_xor(v, off, 64);
                int oj = __shfl_xor(j, off, 64);
                int os = __shfl_xor(src, off, 64);
                if (ov > v || (ov == v && os < src)) { v = ov; j = oj; src = os; }
            }
            selv[k] = __uint_as_float((unsigned int)(bf16_bits_rne(v) << 16));
            selj[k] = j;
            if (lane == src) vals[bp] = -3e38f;
        }
    }

    float mx = selv[0];
    float beta[K_TOP];
    float sum = 0.f;
#pragma unroll
    for (int q = 0; q < K_TOP; q++) { beta[q] = __expf(THETA * (selv[q] - mx)); sum += beta[q]; }
    float rs = 1.0f / sum;

    // lane owns output elems [lane*8, lane*8+8)
    float acc[8];
#pragma unroll
    for (int ee = 0; ee < 8; ee++) acc[ee] = 0.f;
#pragma unroll
    for (int q = 0; q < K_TOP; q++) {
        int j = selj[q];
        float w = beta[q] * rs;
        if (j == row) {   // wave-uniform branch; dominant term stays fp32-exact
            const float4* hr = (const float4*)(h + (size_t)row * D);
            float4 p0 = hr[lane * 2], p1 = hr[lane * 2 + 1];
            acc[0] += w * p0.x; acc[1] += w * p0.y; acc[2] += w * p0.z; acc[3] += w * p0.w;
            acc[4] += w * p1.x; acc[5] += w * p1.y; acc[6] += w * p1.z; acc[7] += w * p1.w;
        } else {          // neighbors (weight ~2e-4): bf16 row x norm
            float wj = w * norms[j];
            u16x8 hv = ((const u16x8*)(hn + (size_t)j * D))[lane];
#pragma unroll
            for (int ee = 0; ee < 8; ee++)
                acc[ee] += wj * __uint_as_float((unsigned int)hv[ee] << 16);
        }
    }
    float4* orow = (float4*)(out + (size_t)row * D);
    orow[lane * 2] = make_float4(acc[0], acc[1], acc[2], acc[3]);
    orow[lane * 2 + 1] = make_float4(acc[4], acc[5], acc[6], acc[7]);
}

extern "C" void kernel_launch(void* const* d_in, const int* in_sizes, int n_in,
                              void* d_out, int out_size, void* d_ws, size_t ws_size,
                              hipStream_t stream) {
    const float* h = (const float*)d_in[0];
    float* out = (float*)d_out;

    char* ws = (char*)d_ws;
    __hip_bfloat16* hn = (__hip_bfloat16*)ws;                    // 8 MB
    size_t off = (size_t)N * D * sizeof(__hip_bfloat16);
    float* norms = (float*)(ws + off);                           // 32 KB
    int* gcnt = (int*)(ws + off + (size_t)N * 4);                // 32 KB
    int* gflag = (int*)(ws + off + (size_t)N * 8);               // 32 KB
    unsigned int* gcand = (unsigned int*)(ws + off + (size_t)N * 12);  // 6 MB

    norm_kernel<<<N / 4, 256, 0, stream>>>(h, hn, norms, gcnt, gflag);
    simtri_kernel<<<NT * (NT + 1) / 2, 256, 0, stream>>>((const unsigned short*)hn,
                                                         gcand, gcnt, gflag);
    gather_kernel<<<N / 4, 256, 0, stream>>>(h, (const unsigned short*)hn, norms,
                                             gcand, gcnt, gflag, out);
}